// Round 7
// baseline (2930.865 us; speedup 1.0000x reference)
//
#include <hip/hip_runtime.h>

// DSDMSR_x8: 13-unit SRCNN cascade, fp32 I/O, bf16 MFMA compute.
// Per 12x12 output tile (256 thr / 4 waves; __launch_bounds__(256,3)):
//   conv1 9x9 1->64 : 2 ci-half passes x 2 m-subset passes (acc 32 AGPR peak)
//                     to stay spill-free within the 168-reg/wave budget
//   conv2 5x5 64->32: dx-major tap groups, K=64 in 2 ci-chunks; B staged
//                     global->VGPR->LDS ring (double-buffered)
//   conv3 5x5 32->1 : per-tap MFMA (K=32), col 0 of C stored
// LDS 49344 B: sH1 4x3216sh | ring 2x10240 (union h2 4x2064sh) | sIn/sW3

typedef unsigned short ushort_t;
typedef __attribute__((ext_vector_type(8))) short short8;   // 8 bf16
typedef __attribute__((ext_vector_type(4))) float f32x4;
typedef __attribute__((ext_vector_type(4))) unsigned int uint4v;

__device__ __forceinline__ float us2f(ushort_t u) { return __uint_as_float(((unsigned int)u) << 16); }
__device__ __forceinline__ ushort_t f2us(float f) {
    unsigned int x = __float_as_uint(f);
    return (ushort_t)((x + 0x7fffu + ((x >> 16) & 1u)) >> 16);
}

#define MFMA16(a, b, c) __builtin_amdgcn_mfma_f32_16x16x32_bf16((a), (b), (c), 0, 0, 0)

// ---------------------------------------------------------------------------
// Weight prep (bf16, MFMA-fragment-friendly layouts):
//  w1t [u][kc3][cig4][ch64][8]          (k = kc*32+cig*8+e, zero for k>=81)
//  w2t [u][c2][dx5][dy5][cig4][co32][8] (ci = c*32+cig*8+e, tap = dy*5+dx)
//  w3t [u][tap25][ci32]
// ---------------------------------------------------------------------------
__global__ __launch_bounds__(256) void prep_weights(
    const float* __restrict__ W1, const float* __restrict__ W2, const float* __restrict__ W3,
    ushort_t* __restrict__ w1t, ushort_t* __restrict__ w2t, ushort_t* __restrict__ w3t)
{
    int i = blockIdx.x * 256 + threadIdx.x;
    if (i < 13 * 3 * 4 * 64 * 8) {           // 79872
        int e = i & 7, ch = (i >> 3) & 63, cig = (i >> 9) & 3;
        int r = i >> 11;                     // u*3 + kc
        int kc = r % 3, u = r / 3;
        int k = kc * 32 + cig * 8 + e;
        w1t[i] = (k < 81) ? f2us(W1[(u * 64 + ch) * 81 + k]) : (ushort_t)0;
    }
    if (i < 665600) {                        // 13*2*25*4*32*8
        int e = i & 7, co = (i >> 3) & 31, cig = (i >> 8) & 3;
        int r = i >> 10;                     // (u*2+c)*25 + s, s = dx*5+dy
        int s = r % 25, cc = r / 25;
        int dx = s / 5, dy = s - 5 * dx;
        int c = cc & 1, u = cc >> 1;
        int tap = dy * 5 + dx;
        int ci = c * 32 + cig * 8 + e;
        w2t[i] = f2us(W2[((u * 32 + co) * 64 + ci) * 25 + tap]);
    }
    if (i < 13 * 25 * 32) {                  // 10400
        int ci = i & 31, r = i >> 5;
        int tap = r % 25, u = r / 25;
        w3t[i] = f2us(W3[(u * 32 + ci) * 25 + tap]);
    }
}

// ---------------------------------------------------------------------------
__global__ __launch_bounds__(256, 3) void srcnn_mfma(
    const float* __restrict__ in, int H, int W,
    const ushort_t* __restrict__ w1t, const ushort_t* __restrict__ w2t,
    const ushort_t* __restrict__ w3t,
    const float* __restrict__ gB1, const float* __restrict__ gB2,
    const float* __restrict__ gB3,
    int unitBase, float* __restrict__ out, int s2)
{
    __shared__ __align__(16) char smem[49344];
    ushort_t* sH1  = (ushort_t*)smem;             // 4 planes x 3216 shorts (16-short skew pad)
    char*     sRing = smem + 25728;               // 2 x 10240 B  (union: h2 4 x 2064 shorts)
    float*    sIn  = (float*)(smem + 46208);      // 784 f32 (conv1 only)
    ushort_t* sW3  = (ushort_t*)(smem + 46208);   // 800 u16 (after conv1)
    ushort_t* sH2  = (ushort_t*)sRing;

    const int t = threadIdx.x, lane = t & 63, wv = t >> 6;
    const int q = lane >> 4, l15 = lane & 15;
    const int z = blockIdx.z;
    const int k4 = (s2 == 2) ? (z >> 2) : 0;
    const int b  = (s2 == 2) ? (z & 3)  : z;
    const int unit = unitBase + k4;
    const int ppx = k4 & 1, ppy = k4 >> 1;
    const int ox0 = blockIdx.x * 12, oy0 = blockIdx.y * 12;
    const int outW = W * s2;
    const int outH = H * s2;
    const float* inb = in + (size_t)b * H * W;

    const char* w2u = (const char*)w2t + (size_t)unit * 102400;

    // --- conv2 B staging: global -> VGPR (pf) -> LDS ring slot p&1 ---
    uint4v pf[3];
    auto ldGroup = [&](int p) {
        if (p < 10) {
            const char* src = w2u + (size_t)p * 10240 + lane * 16;
#pragma unroll
            for (int j = 0; j < 3; ++j) {
                int ck = wv + j * 4;
                if (ck < 10) pf[j] = *(const uint4v*)(src + ck * 1024);
            }
        }
    };
    auto wrGroup = [&](int p) {
        if (p < 10) {
            char* dst = sRing + (p & 1) * 10240 + lane * 16;
#pragma unroll
            for (int j = 0; j < 3; ++j) {
                int ck = wv + j * 4;
                if (ck < 10) *(uint4v*)(dst + ck * 1024) = pf[j];
            }
        }
    };

    ldGroup(0);

    // stage input 28x28 (origin -8, zero-padded)
    for (int idx = t; idx < 784; idx += 256) {
        int y = idx / 28, x = idx - 28 * y;
        int gy = oy0 - 8 + y, gx = ox0 - 8 + x;
        sIn[idx] = (gy >= 0 && gy < H && gx >= 0 && gx < W) ? inb[(size_t)gy * W + gx] : 0.f;
    }
    __syncthreads();
    wrGroup(0);   // barrier drained vmcnt; frees pf before conv1

    const ushort_t* w1u = w1t + (size_t)unit * (3 * 4 * 64 * 8);

    f32x4 acc2[4][2];
#pragma unroll
    for (int i = 0; i < 4; ++i) { acc2[i][0] = (f32x4){0.f,0.f,0.f,0.f}; acc2[i][1] = (f32x4){0.f,0.f,0.f,0.f}; }

    for (int c = 0; c < 2; ++c) {
        // ---- conv1 half (ci [c*32, c*32+32)) in 2 m-subset passes ----
        float bias0 = gB1[unit * 64 + c * 32 + l15];
        float bias1 = gB1[unit * 64 + c * 32 + 16 + l15];

#pragma unroll
        for (int ms = 0; ms < 2; ++ms) {
            const int mbase = ms * 16;
            const int nim = ms ? 3 : 4;              // m-tiles: 0..15 then 16..24
            f32x4 acc1h[4][2];
#pragma unroll
            for (int i = 0; i < 4; ++i) { acc1h[i][0] = (f32x4){0.f,0.f,0.f,0.f}; acc1h[i][1] = (f32x4){0.f,0.f,0.f,0.f}; }

            for (int kc = 0; kc < 3; ++kc) {
                short8 bh0 = *(const short8*)&w1u[((kc * 4 + q) * 64 + (c * 32 + l15)) * 8];
                short8 bh1 = *(const short8*)&w1u[((kc * 4 + q) * 64 + (c * 32 + 16 + l15)) * 8];
                int toff8[8];
#pragma unroll
                for (int j = 0; j < 8; ++j) {
                    int k = kc * 32 + q * 8 + j;
                    if (k < 81) { int ty = (k * 57) >> 9; toff8[j] = ty * 28 + (k - 9 * ty); }
                    else toff8[j] = -1;
                }
#pragma unroll
                for (int im = 0; im < 4; ++im) {
                    if (im < nim) {
                        int m = mbase + wv + im * 4;
                        if (m < 25) {
                            int px = m * 16 + l15;            // 0..399 (20x20 h1 grid)
                            int py1 = (px * 205) >> 12;
                            int base = py1 * 28 + (px - 20 * py1);
                            union { short8 v; ushort_t u[8]; } a;
#pragma unroll
                            for (int j = 0; j < 8; ++j) {
                                int o = toff8[j];
                                a.u[j] = (o >= 0) ? f2us(sIn[base + o]) : (ushort_t)0;
                            }
                            acc1h[im][0] = MFMA16(a.v, bh0, acc1h[im][0]);
                            acc1h[im][1] = MFMA16(a.v, bh1, acc1h[im][1]);
                        }
                    }
                }
            }

            // writeback this m-subset, layout [cig][px][8], skewed planes
#pragma unroll
            for (int im = 0; im < 4; ++im) {
                if (im < nim) {
                    int m = mbase + wv + im * 4;
                    if (m < 25) {
#pragma unroll
                        for (int nn = 0; nn < 2; ++nn) {
                            float bias = nn ? bias1 : bias0;
                            int cig = (nn * 16 + l15) >> 3;
                            int e   = l15 & 7;
#pragma unroll
                            for (int r = 0; r < 4; ++r) {
                                int px = m * 16 + q * 4 + r;
                                int py1 = (px * 205) >> 12;
                                int px1 = px - 20 * py1;
                                int gy = oy0 - 4 + py1, gx = ox0 - 4 + px1;
                                float v = fmaxf(acc1h[im][nn][r] + bias, 0.f);
                                if (!(gy >= 0 && gy < H && gx >= 0 && gx < W)) v = 0.f;
                                sH1[cig * 3216 + px * 8 + e] = f2us(v);
                            }
                        }
                    }
                }
            }
        }
        __syncthreads();

        // ---- conv2: dx-major groups, A row-reuse across dy ----
        for (int dx = 0; dx < 5; ++dx) {
            int p = c * 5 + dx;
            const ushort_t* ring = (const ushort_t*)(sRing + (p & 1) * 10240);
            short8 Bf[5][2];
#pragma unroll
            for (int dy = 0; dy < 5; ++dy) {
                Bf[dy][0] = *(const short8*)&ring[dy * 1024 + q * 256 + l15 * 8];
                Bf[dy][1] = *(const short8*)&ring[dy * 1024 + q * 256 + (16 + l15) * 8];
            }
            ldGroup(p + 1);
#pragma unroll
            for (int rel = 0; rel < 8; ++rel) {
                int row = wv * 4 + rel;
                short8 a = *(const short8*)&sH1[q * 3216 + (row * 20 + l15 + dx) * 8];
#pragma unroll
                for (int dy = 0; dy < 5; ++dy) {
                    if (dy >= (rel - 3 < 0 ? 0 : rel - 3) && dy <= (rel < 4 ? rel : 4)) {
                        int im = rel - dy;
                        acc2[im][0] = MFMA16(a, Bf[dy][0], acc2[im][0]);
                        acc2[im][1] = MFMA16(a, Bf[dy][1], acc2[im][1]);
                    }
                }
            }
            wrGroup(p + 1);
            __syncthreads();
        }
    }

    // ---- h2 writeback [cog4][px256][8] into ring region (skewed stride 2064) ----
    {
        float bias0 = gB2[unit * 32 + l15];
        float bias1 = gB2[unit * 32 + 16 + l15];
#pragma unroll
        for (int im = 0; im < 4; ++im) {
            int hy = wv * 4 + im;
#pragma unroll
            for (int n = 0; n < 2; ++n) {
                int co = n * 16 + l15;
                float bias = n ? bias1 : bias0;
                int cog = co >> 3, e = co & 7;
#pragma unroll
                for (int r = 0; r < 4; ++r) {
                    int hx = q * 4 + r;
                    int gy = oy0 - 2 + hy, gx = ox0 - 2 + hx;
                    float v = fmaxf(acc2[im][n][r] + bias, 0.f);
                    if (!(gy >= 0 && gy < H && gx >= 0 && gx < W)) v = 0.f;
                    sH2[cog * 2064 + (hy * 16 + hx) * 8 + e] = f2us(v);
                }
            }
        }
    }
    // stage w3 into sIn region (dead after conv1)
    {
        const ushort_t* w3u = w3t + unit * 800;
        for (int i = t; i < 800; i += 256) sW3[i] = w3u[i];
    }
    __syncthreads();

    // ---- conv3: per-tap MFMA, K=32, 9 m-tiles over 144 out px ----
    float b3 = gB3[unit];
    int nm = (wv == 0) ? 3 : 2;
    for (int jm = 0; jm < nm; ++jm) {
        int mt = wv + 4 * jm;                        // 0..8
        int p = mt * 16 + l15;                       // 0..143
        int oy2 = (p * 683) >> 13, ox2 = p - 12 * oy2;
        f32x4 acc = (f32x4){0.f, 0.f, 0.f, 0.f};
        for (int tap = 0; tap < 25; ++tap) {
            int dy = (tap * 13) >> 6, dx = tap - 5 * dy;
            int h2px = (oy2 + dy) * 16 + ox2 + dx;
            short8 a = *(const short8*)&sH2[q * 2064 + h2px * 8];
            short8 w = *(const short8*)&sW3[tap * 32 + q * 8];
            acc = MFMA16(a, w, acc);
        }
        if (l15 == 0) {
#pragma unroll
            for (int r = 0; r < 4; ++r) {
                int pp = mt * 16 + q * 4 + r;
                int oy = (pp * 683) >> 13, ox = pp - 12 * oy;
                int gy = oy0 + oy, gx = ox0 + ox;
                if (gy < H && gx < W) {
                    size_t o = (size_t)b * outW * outH + (size_t)(gy * s2 + ppy) * outW + (gx * s2 + ppx);
                    out[o] = acc[r] + b3;
                }
            }
        }
    }
}

// ---------------------------------------------------------------------------
// MSF input: up4(out_x2) + up2(out_x4) + out_x8 (bilinear, half-pixel, clamped)
// ---------------------------------------------------------------------------
__device__ __forceinline__ void ax_w(int i, float inv_s, int n, int& i0, int& i1, float& w1) {
    float c  = (i + 0.5f) * inv_s - 0.5f;
    float fl = floorf(c);
    w1 = c - fl;
    int ii = (int)fl;
    i0 = ii < 0 ? 0 : ii;
    i1 = (ii + 1 >= n) ? (n - 1) : (ii + 1);
}

__global__ __launch_bounds__(256) void msf_in_kernel(
    const float* __restrict__ f2, const float* __restrict__ f4,
    const float* __restrict__ f8, float* __restrict__ dst)
{
    int idx = blockIdx.x * 256 + threadIdx.x;   // 4*512*512
    int x = idx & 511;
    int y = (idx >> 9) & 511;
    int b = idx >> 18;

    int y0, y1, x0, x1;
    float wy, wx;

    ax_w(y, 0.25f, 128, y0, y1, wy);
    ax_w(x, 0.25f, 128, x0, x1, wx);
    const float* p2 = f2 + (size_t)b * 16384;
    float v4 = (1.f - wy) * ((1.f - wx) * p2[y0 * 128 + x0] + wx * p2[y0 * 128 + x1])
             +        wy  * ((1.f - wx) * p2[y1 * 128 + x0] + wx * p2[y1 * 128 + x1]);

    ax_w(y, 0.5f, 256, y0, y1, wy);
    ax_w(x, 0.5f, 256, x0, x1, wx);
    const float* p4 = f4 + (size_t)b * 65536;
    float v2 = (1.f - wy) * ((1.f - wx) * p4[y0 * 256 + x0] + wx * p4[y0 * 256 + x1])
             +        wy  * ((1.f - wx) * p4[y1 * 256 + x0] + wx * p4[y1 * 256 + x1]);

    dst[idx] = v4 + v2 + f8[idx];
}

// ---------------------------------------------------------------------------
extern "C" void kernel_launch(void* const* d_in, const int* in_sizes, int n_in,
                              void* d_out, int out_size, void* d_ws, size_t ws_size,
                              hipStream_t stream)
{
    (void)in_sizes; (void)n_in; (void)out_size; (void)ws_size;

    const float* image = (const float*)d_in[0];
    const float* W1    = (const float*)d_in[1];
    const float* B1    = (const float*)d_in[2];
    const float* W2    = (const float*)d_in[3];
    const float* B2    = (const float*)d_in[4];
    const float* W3    = (const float*)d_in[5];
    const float* B3    = (const float*)d_in[6];

    float* out = (float*)d_out;
    float* o2 = out;                 // (4,1,128,128)
    float* o4 = out + 65536;         // (4,1,256,256)
    float* o8 = out + 327680;        // (4,1,512,512)
    float* om = out + 1376256;       // msf (4,1,512,512)

    float*    fm  = (float*)d_ws;                              // 4 MB
    ushort_t* w1t = (ushort_t*)((char*)d_ws + 4194304);        // 79872 u16
    ushort_t* w2t = (ushort_t*)((char*)d_ws + 4354048);        // 665600 u16
    ushort_t* w3t = (ushort_t*)((char*)d_ws + 5685248);        // 10400 u16

    prep_weights<<<2600, 256, 0, stream>>>(W1, W2, W3, w1t, w2t, w3t);

    srcnn_mfma<<<dim3(6, 6, 16), 256, 0, stream>>>(
        image, 64, 64, w1t, w2t, w3t, B1, B2, B3, 0, o2, 2);
    srcnn_mfma<<<dim3(11, 11, 16), 256, 0, stream>>>(
        o2, 128, 128, w1t, w2t, w3t, B1, B2, B3, 4, o4, 2);
    srcnn_mfma<<<dim3(22, 22, 16), 256, 0, stream>>>(
        o4, 256, 256, w1t, w2t, w3t, B1, B2, B3, 8, o8, 2);
    msf_in_kernel<<<4096, 256, 0, stream>>>(o2, o4, o8, fm);
    srcnn_mfma<<<dim3(43, 43, 4), 256, 0, stream>>>(
        fm, 512, 512, w1t, w2t, w3t, B1, B2, B3, 12, om, 1);
}

// Round 8
// 1518.542 us; speedup vs baseline: 1.9301x; 1.9301x over previous
//
#include <hip/hip_runtime.h>

// DSDMSR_x8: 13-unit SRCNN cascade, fp32 I/O, bf16 MFMA compute.
// Per 12x12 output tile (256 thr / 4 waves, __launch_bounds__(256,2)):
// SPILL-FREE STRUCTURE: the three convs have disjoint accumulator lifetimes.
//   phase 1: conv1 9x9 1->64, two ci-halves (acc 56 AGPR), ALL h1 -> LDS
//   phase 2: conv2 5x5 64->32 (acc 32 AGPR), B double-buffered in REGISTERS
//            direct from L2 (no LDS ring, no extra barriers)
//   phase 3: conv3 5x5 32->1 per-tap MFMA (K=32)
// LDS 54464 B: sH1 8 planes x 3208 sh (skew +4 banks/plane) | sIn 3136 (union sW3)
//              h2 unioned into sH1 after conv2.

typedef unsigned short ushort_t;
typedef __attribute__((ext_vector_type(8))) short short8;   // 8 bf16
typedef __attribute__((ext_vector_type(4))) float f32x4;

__device__ __forceinline__ float us2f(ushort_t u) { return __uint_as_float(((unsigned int)u) << 16); }
__device__ __forceinline__ ushort_t f2us(float f) {
    unsigned int x = __float_as_uint(f);
    return (ushort_t)((x + 0x7fffu + ((x >> 16) & 1u)) >> 16);
}

#define MFMA16(a, b, c) __builtin_amdgcn_mfma_f32_16x16x32_bf16((a), (b), (c), 0, 0, 0)

// ---------------------------------------------------------------------------
// Weight prep (bf16, MFMA-fragment-friendly layouts):
//  w1t [u][kc3][cig4][ch64][8]          (k = kc*32+cig*8+e, zero for k>=81)
//  w2t [u][c2][dx5][dy5][cig4][co32][8] (ci = c*32+cig*8+e, tap = dy*5+dx)
//  w3t [u][tap25][ci32]
// ---------------------------------------------------------------------------
__global__ __launch_bounds__(256) void prep_weights(
    const float* __restrict__ W1, const float* __restrict__ W2, const float* __restrict__ W3,
    ushort_t* __restrict__ w1t, ushort_t* __restrict__ w2t, ushort_t* __restrict__ w3t)
{
    int i = blockIdx.x * 256 + threadIdx.x;
    if (i < 13 * 3 * 4 * 64 * 8) {           // 79872
        int e = i & 7, ch = (i >> 3) & 63, cig = (i >> 9) & 3;
        int r = i >> 11;                     // u*3 + kc
        int kc = r % 3, u = r / 3;
        int k = kc * 32 + cig * 8 + e;
        w1t[i] = (k < 81) ? f2us(W1[(u * 64 + ch) * 81 + k]) : (ushort_t)0;
    }
    if (i < 665600) {                        // 13*2*25*4*32*8
        int e = i & 7, co = (i >> 3) & 31, cig = (i >> 8) & 3;
        int r = i >> 10;                     // (u*2+c)*25 + s, s = dx*5+dy
        int s = r % 25, cc = r / 25;
        int dx = s / 5, dy = s - 5 * dx;
        int c = cc & 1, u = cc >> 1;
        int tap = dy * 5 + dx;
        int ci = c * 32 + cig * 8 + e;
        w2t[i] = f2us(W2[((u * 32 + co) * 64 + ci) * 25 + tap]);
    }
    if (i < 13 * 25 * 32) {                  // 10400
        int ci = i & 31, r = i >> 5;
        int tap = r % 25, u = r / 25;
        w3t[i] = f2us(W3[(u * 32 + ci) * 25 + tap]);
    }
}

// ---------------------------------------------------------------------------
__global__ __launch_bounds__(256, 2) void srcnn_mfma(
    const float* __restrict__ in, int H, int W,
    const ushort_t* __restrict__ w1t, const ushort_t* __restrict__ w2t,
    const ushort_t* __restrict__ w3t,
    const float* __restrict__ gB1, const float* __restrict__ gB2,
    const float* __restrict__ gB3,
    int unitBase, float* __restrict__ out, int s2)
{
    __shared__ __align__(16) char smem[54464];
    ushort_t* sH1 = (ushort_t*)smem;              // 8 planes x 3208 shorts = 51328 B
    float*    sIn = (float*)(smem + 51328);       // 784 f32 (conv1 only)
    ushort_t* sW3 = (ushort_t*)(smem + 51328);    // 800 u16 (after conv1)
    ushort_t* sH2 = (ushort_t*)smem;              // h2 4 x 2064 shorts (after conv2)

    const int t = threadIdx.x, lane = t & 63, wv = t >> 6;
    const int q = lane >> 4, l15 = lane & 15;
    const int z = blockIdx.z;
    const int k4 = (s2 == 2) ? (z >> 2) : 0;
    const int b  = (s2 == 2) ? (z & 3)  : z;
    const int unit = unitBase + k4;
    const int ppx = k4 & 1, ppy = k4 >> 1;
    const int ox0 = blockIdx.x * 12, oy0 = blockIdx.y * 12;
    const int outW = W * s2;
    const int outH = H * s2;
    const float* inb = in + (size_t)b * H * W;

    const char* w2u = (const char*)w2t + (size_t)unit * 102400;

    // conv2 B: register double-buffer, loaded straight from global/L2.
    // buf[dy*2+n] for group p (c=p/5, dx=p%5).
    short8 Ba[10], Bb[10];
    auto loadB = [&](short8* buf, int p) {
        const char* g = w2u + (size_t)p * 10240 + q * 512 + l15 * 16;
#pragma unroll
        for (int dy = 0; dy < 5; ++dy) {
            buf[dy * 2 + 0] = *(const short8*)(g + dy * 2048);
            buf[dy * 2 + 1] = *(const short8*)(g + dy * 2048 + 256);
        }
    };
    loadB(Ba, 0);   // in flight through input staging + conv1

    // stage input 28x28 (origin -8, zero-padded)
    for (int idx = t; idx < 784; idx += 256) {
        int y = idx / 28, x = idx - 28 * y;
        int gy = oy0 - 8 + y, gx = ox0 - 8 + x;
        sIn[idx] = (gy >= 0 && gy < H && gx >= 0 && gx < W) ? inb[(size_t)gy * W + gx] : 0.f;
    }
    __syncthreads();

    const ushort_t* w1u = w1t + (size_t)unit * (3 * 4 * 64 * 8);

    // ---- phase 1: conv1, two ci-halves; only acc1h (56 AGPR) live ----
    for (int c = 0; c < 2; ++c) {
        f32x4 acc1h[7][2];
#pragma unroll
        for (int i = 0; i < 7; ++i) { acc1h[i][0] = (f32x4){0.f,0.f,0.f,0.f}; acc1h[i][1] = (f32x4){0.f,0.f,0.f,0.f}; }

        for (int kc = 0; kc < 3; ++kc) {
            short8 bh0 = *(const short8*)&w1u[((kc * 4 + q) * 64 + (c * 32 + l15)) * 8];
            short8 bh1 = *(const short8*)&w1u[((kc * 4 + q) * 64 + (c * 32 + 16 + l15)) * 8];
            int toff8[8];
#pragma unroll
            for (int j = 0; j < 8; ++j) {
                int k = kc * 32 + q * 8 + j;
                if (k < 81) { int ty = (k * 57) >> 9; toff8[j] = ty * 28 + (k - 9 * ty); }
                else toff8[j] = -1;
            }
#pragma unroll
            for (int im = 0; im < 7; ++im) {
                int m = wv + im * 4;
                if (m < 25) {
                    int px = m * 16 + l15;            // 0..399 (20x20 h1 grid)
                    int py1 = (px * 205) >> 12;
                    int base = py1 * 28 + (px - 20 * py1);
                    union { short8 v; ushort_t u[8]; } a;
#pragma unroll
                    for (int j = 0; j < 8; ++j) {
                        int o = toff8[j];
                        a.u[j] = (o >= 0) ? f2us(sIn[base + o]) : (ushort_t)0;
                    }
                    acc1h[im][0] = MFMA16(a.v, bh0, acc1h[im][0]);
                    acc1h[im][1] = MFMA16(a.v, bh1, acc1h[im][1]);
                }
            }
        }

        // writeback this half: sH1 [cig8][px400][8], plane stride 3208 (skew)
        float bias0 = gB1[unit * 64 + c * 32 + l15];
        float bias1 = gB1[unit * 64 + c * 32 + 16 + l15];
#pragma unroll
        for (int im = 0; im < 7; ++im) {
            int m = wv + im * 4;
            if (m < 25) {
#pragma unroll
                for (int nn = 0; nn < 2; ++nn) {
                    float bias = nn ? bias1 : bias0;
                    int cig = c * 4 + ((nn * 16 + l15) >> 3);
                    int e   = l15 & 7;
#pragma unroll
                    for (int r = 0; r < 4; ++r) {
                        int px = m * 16 + q * 4 + r;
                        int py1 = (px * 205) >> 12;
                        int px1 = px - 20 * py1;
                        int gy = oy0 - 4 + py1, gx = ox0 - 4 + px1;
                        float v = fmaxf(acc1h[im][nn][r] + bias, 0.f);
                        if (!(gy >= 0 && gy < H && gx >= 0 && gx < W)) v = 0.f;
                        sH1[cig * 3208 + px * 8 + e] = f2us(v);
                    }
                }
            }
        }
    }
    __syncthreads();   // all h1 written; all sIn reads done

    // stage w3 into sIn region (dead); visible to conv3 via the post-h2 barrier
    {
        const ushort_t* w3u = w3t + unit * 800;
        for (int i = t; i < 800; i += 256) sW3[i] = w3u[i];
    }

    // ---- phase 2: conv2; only acc2 (32 AGPR) + B regs live ----
    f32x4 acc2[4][2];
#pragma unroll
    for (int i = 0; i < 4; ++i) { acc2[i][0] = (f32x4){0.f,0.f,0.f,0.f}; acc2[i][1] = (f32x4){0.f,0.f,0.f,0.f}; }

    auto mfmaGroup = [&](int p, const short8* Bf) {
        int c = p / 5, dx = p - 5 * (p / 5);
        const ushort_t* base = &sH1[(c * 4 + q) * 3208];
#pragma unroll
        for (int rel = 0; rel < 8; ++rel) {
            int row = wv * 4 + rel;
            short8 a = *(const short8*)&base[(row * 20 + l15 + dx) * 8];
#pragma unroll
            for (int dy = 0; dy < 5; ++dy) {
                if (dy >= (rel - 3 < 0 ? 0 : rel - 3) && dy <= (rel < 4 ? rel : 4)) {
                    int im = rel - dy;
                    acc2[im][0] = MFMA16(a, Bf[dy * 2 + 0], acc2[im][0]);
                    acc2[im][1] = MFMA16(a, Bf[dy * 2 + 1], acc2[im][1]);
                }
            }
        }
    };

#pragma unroll
    for (int h = 0; h < 5; ++h) {
        int p = 2 * h;
        if (p < 9) loadB(Bb, p + 1);
        mfmaGroup(p, Ba);
        if (p + 1 < 9) loadB(Ba, p + 2);
        mfmaGroup(p + 1, Bb);
    }
    __syncthreads();   // all sH1 reads done before h2 overwrites it

    // ---- h2 writeback [cog4][px256][8], stride 2064, into sH1 region ----
    {
        float bias0 = gB2[unit * 32 + l15];
        float bias1 = gB2[unit * 32 + 16 + l15];
#pragma unroll
        for (int im = 0; im < 4; ++im) {
            int hy = wv * 4 + im;
#pragma unroll
            for (int n = 0; n < 2; ++n) {
                int co = n * 16 + l15;
                float bias = n ? bias1 : bias0;
                int cog = co >> 3, e = co & 7;
#pragma unroll
                for (int r = 0; r < 4; ++r) {
                    int hx = q * 4 + r;
                    int gy = oy0 - 2 + hy, gx = ox0 - 2 + hx;
                    float v = fmaxf(acc2[im][n][r] + bias, 0.f);
                    if (!(gy >= 0 && gy < H && gx >= 0 && gx < W)) v = 0.f;
                    sH2[cog * 2064 + (hy * 16 + hx) * 8 + e] = f2us(v);
                }
            }
        }
    }
    __syncthreads();

    // ---- phase 3: conv3 per-tap MFMA, K=32, 9 m-tiles over 144 out px ----
    float b3 = gB3[unit];
    int nm = (wv == 0) ? 3 : 2;
    for (int jm = 0; jm < nm; ++jm) {
        int mt = wv + 4 * jm;                        // 0..8
        int p = mt * 16 + l15;                       // 0..143
        int oy2 = (p * 683) >> 13, ox2 = p - 12 * oy2;
        f32x4 acc = (f32x4){0.f, 0.f, 0.f, 0.f};
        for (int tap = 0; tap < 25; ++tap) {
            int dy = (tap * 13) >> 6, dx = tap - 5 * dy;
            int h2px = (oy2 + dy) * 16 + ox2 + dx;
            short8 a = *(const short8*)&sH2[q * 2064 + h2px * 8];
            short8 w = *(const short8*)&sW3[tap * 32 + q * 8];
            acc = MFMA16(a, w, acc);
        }
        if (l15 == 0) {
#pragma unroll
            for (int r = 0; r < 4; ++r) {
                int pp = mt * 16 + q * 4 + r;
                int oy = (pp * 683) >> 13, ox = pp - 12 * oy;
                int gy = oy0 + oy, gx = ox0 + ox;
                if (gy < H && gx < W) {
                    size_t o = (size_t)b * outW * outH + (size_t)(gy * s2 + ppy) * outW + (gx * s2 + ppx);
                    out[o] = acc[r] + b3;
                }
            }
        }
    }
}

// ---------------------------------------------------------------------------
// MSF input: up4(out_x2) + up2(out_x4) + out_x8 (bilinear, half-pixel, clamped)
// ---------------------------------------------------------------------------
__device__ __forceinline__ void ax_w(int i, float inv_s, int n, int& i0, int& i1, float& w1) {
    float c  = (i + 0.5f) * inv_s - 0.5f;
    float fl = floorf(c);
    w1 = c - fl;
    int ii = (int)fl;
    i0 = ii < 0 ? 0 : ii;
    i1 = (ii + 1 >= n) ? (n - 1) : (ii + 1);
}

__global__ __launch_bounds__(256) void msf_in_kernel(
    const float* __restrict__ f2, const float* __restrict__ f4,
    const float* __restrict__ f8, float* __restrict__ dst)
{
    int idx = blockIdx.x * 256 + threadIdx.x;   // 4*512*512
    int x = idx & 511;
    int y = (idx >> 9) & 511;
    int b = idx >> 18;

    int y0, y1, x0, x1;
    float wy, wx;

    ax_w(y, 0.25f, 128, y0, y1, wy);
    ax_w(x, 0.25f, 128, x0, x1, wx);
    const float* p2 = f2 + (size_t)b * 16384;
    float v4 = (1.f - wy) * ((1.f - wx) * p2[y0 * 128 + x0] + wx * p2[y0 * 128 + x1])
             +        wy  * ((1.f - wx) * p2[y1 * 128 + x0] + wx * p2[y1 * 128 + x1]);

    ax_w(y, 0.5f, 256, y0, y1, wy);
    ax_w(x, 0.5f, 256, x0, x1, wx);
    const float* p4 = f4 + (size_t)b * 65536;
    float v2 = (1.f - wy) * ((1.f - wx) * p4[y0 * 256 + x0] + wx * p4[y0 * 256 + x1])
             +        wy  * ((1.f - wx) * p4[y1 * 256 + x0] + wx * p4[y1 * 256 + x1]);

    dst[idx] = v4 + v2 + f8[idx];
}

// ---------------------------------------------------------------------------
extern "C" void kernel_launch(void* const* d_in, const int* in_sizes, int n_in,
                              void* d_out, int out_size, void* d_ws, size_t ws_size,
                              hipStream_t stream)
{
    (void)in_sizes; (void)n_in; (void)out_size; (void)ws_size;

    const float* image = (const float*)d_in[0];
    const float* W1    = (const float*)d_in[1];
    const float* B1    = (const float*)d_in[2];
    const float* W2    = (const float*)d_in[3];
    const float* B2    = (const float*)d_in[4];
    const float* W3    = (const float*)d_in[5];
    const float* B3    = (const float*)d_in[6];

    float* out = (float*)d_out;
    float* o2 = out;                 // (4,1,128,128)
    float* o4 = out + 65536;         // (4,1,256,256)
    float* o8 = out + 327680;        // (4,1,512,512)
    float* om = out + 1376256;       // msf (4,1,512,512)

    float*    fm  = (float*)d_ws;                              // 4 MB
    ushort_t* w1t = (ushort_t*)((char*)d_ws + 4194304);        // 79872 u16
    ushort_t* w2t = (ushort_t*)((char*)d_ws + 4354048);        // 665600 u16
    ushort_t* w3t = (ushort_t*)((char*)d_ws + 5685248);        // 10400 u16

    prep_weights<<<2600, 256, 0, stream>>>(W1, W2, W3, w1t, w2t, w3t);

    srcnn_mfma<<<dim3(6, 6, 16), 256, 0, stream>>>(
        image, 64, 64, w1t, w2t, w3t, B1, B2, B3, 0, o2, 2);
    srcnn_mfma<<<dim3(11, 11, 16), 256, 0, stream>>>(
        o2, 128, 128, w1t, w2t, w3t, B1, B2, B3, 4, o4, 2);
    srcnn_mfma<<<dim3(22, 22, 16), 256, 0, stream>>>(
        o4, 256, 256, w1t, w2t, w3t, B1, B2, B3, 8, o8, 2);
    msf_in_kernel<<<4096, 256, 0, stream>>>(o2, o4, o8, fm);
    srcnn_mfma<<<dim3(43, 43, 4), 256, 0, stream>>>(
        fm, 512, 512, w1t, w2t, w3t, B1, B2, B3, 12, om, 1);
}